// Round 10
// baseline (143.321 us; speedup 1.0000x reference)
//
#include <hip/hip_runtime.h>
#include <math.h>

#define HH 1024
#define WW 1024
#define OH 1020
#define OW 1020
#define KS 5
#define CHUNK 60      // 17*60 = 1020 exactly
#define NCHUNK 17
#define TPB 512       // 512 threads * T=2 cols = 1024 columns covered
#define T 2
#define NIMG 48       // B*C = 16*3
#define CCH 3

// GK = 5 * sqrt(2*pi) * sigma^2, sigma=2
#define GKC 50.132565492620004f
#define EPSC 1e-6f
// Windows with |box_sum| below this get their sum recomputed in replicated
// numpy-f32 order (the ratio is rounding-noise-sensitive there).
#define RECOMP_T 1e-4f

// numpy order: inner (contiguous col) axis n=5 -> sequential fold; outer (row)
// axis -> sequential left-fold of the row sums. KEEP IDENTICAL (R3-R9 passed).
__device__ __forceinline__ float win25_np(const float* __restrict__ p) {
    float s = 0.0f;
    #pragma unroll
    for (int r = 0; r < KS; ++r) {
        const float* q = p + (size_t)r * WW;
        float t = q[0];
        t += q[1]; t += q[2]; t += q[3]; t += q[4];
        s += t;
    }
    return s;
}

// Load 6 consecutive floats (three float2), produce 2 horizontal 5-window sums
// (signed s, abs a). Summation order identical to R4-R9's load_row s[0],s[1].
__device__ __forceinline__ void row2(const float* __restrict__ row,
                                     float2& s, float2& a) {
    float2 u = *reinterpret_cast<const float2*>(row);
    float2 v = *reinterpret_cast<const float2*>(row + 2);
    float2 w = *reinterpret_cast<const float2*>(row + 4);
    float s0 = ((u.x + u.y) + (v.x + v.y)) + w.x;
    s.x = s0;
    s.y = s0 - u.x + w.y;
    float p0 = fabsf(u.x), p1 = fabsf(u.y), p2 = fabsf(v.x), p3 = fabsf(v.y);
    float q0 = fabsf(w.x), q1 = fabsf(w.y);
    float a0 = ((p0 + p1) + (p2 + p3)) + q0;
    a.x = a0;
    a.y = a0 - p0 + q1;
}

__global__ __launch_bounds__(TPB)   // natural VGPR; R7 showed pinning spills
void rtv_partial(const float* __restrict__ gh, const float* __restrict__ gw,
                 const float* __restrict__ gam, double* __restrict__ partial)
{
    const int x0  = (int)threadIdx.x * T;   // first output column of this thread
    const int img = blockIdx.y;             // b*C + c
    const int y0  = blockIdx.x * CHUNK;     // first output row (chunk always full)

    float acc = 0.0f;

    if (x0 < OW) {                          // threads 510,511 idle
        const float* __restrict__ ph = gh + (size_t)img * HH * WW;
        const float* __restrict__ pw = gw + (size_t)img * HH * WW;

        // 5-slot rings of horizontal window sums, both planes (R3-style shape)
        float2 sh[KS], ah[KS], sw[KS], aw[KS];
        #pragma unroll
        for (int i = 0; i < KS - 1; ++i) {
            row2(ph + (size_t)(y0 + i) * WW + x0, sh[i], ah[i]);
            row2(pw + (size_t)(y0 + i) * WW + x0, sw[i], aw[i]);
        }

        // simple rolling loop (R3's shape: low VGPR, compiler renames shifts)
        for (int y = y0; y < y0 + CHUNK; ++y) {
            row2(ph + (size_t)(y + 4) * WW + x0, sh[KS - 1], ah[KS - 1]);
            row2(pw + (size_t)(y + 4) * WW + x0, sw[KS - 1], aw[KS - 1]);

            // fresh 5-tap vertical sums, same order as R3-R9 (componentwise)
            float vs_h0 = ((sh[0].x + sh[1].x) + (sh[2].x + sh[3].x)) + sh[4].x;
            float vs_h1 = ((sh[0].y + sh[1].y) + (sh[2].y + sh[3].y)) + sh[4].y;
            float va_h0 = ((ah[0].x + ah[1].x) + (ah[2].x + ah[3].x)) + ah[4].x;
            float va_h1 = ((ah[0].y + ah[1].y) + (ah[2].y + ah[3].y)) + ah[4].y;
            float vs_w0 = ((sw[0].x + sw[1].x) + (sw[2].x + sw[3].x)) + sw[4].x;
            float vs_w1 = ((sw[0].y + sw[1].y) + (sw[2].y + sw[3].y)) + sw[4].y;
            float va_w0 = ((aw[0].x + aw[1].x) + (aw[2].x + aw[3].x)) + aw[4].x;
            float va_w1 = ((aw[0].y + aw[1].y) + (aw[2].y + aw[3].y)) + aw[4].y;

            float den_h0, den_h1, den_w0, den_w1;
            if (__builtin_expect(fabsf(vs_h0) < RECOMP_T, 0)) {
                float s32 = win25_np(ph + (size_t)y * WW + x0);
                den_h0 = fabsf(GKC * s32) + EPSC;
            } else den_h0 = fabsf(GKC * vs_h0) + EPSC;
            if (__builtin_expect(fabsf(vs_h1) < RECOMP_T, 0)) {
                float s32 = win25_np(ph + (size_t)y * WW + x0 + 1);
                den_h1 = fabsf(GKC * s32) + EPSC;
            } else den_h1 = fabsf(GKC * vs_h1) + EPSC;
            if (__builtin_expect(fabsf(vs_w0) < RECOMP_T, 0)) {
                float s32 = win25_np(pw + (size_t)y * WW + x0);
                den_w0 = fabsf(GKC * s32) + EPSC;
            } else den_w0 = fabsf(GKC * vs_w0) + EPSC;
            if (__builtin_expect(fabsf(vs_w1) < RECOMP_T, 0)) {
                float s32 = win25_np(pw + (size_t)y * WW + x0 + 1);
                den_w1 = fabsf(GKC * s32) + EPSC;
            } else den_w1 = fabsf(GKC * vs_w1) + EPSC;

            acc += (GKC * va_h0) * __builtin_amdgcn_rcpf(den_h0)
                 + (GKC * va_h1) * __builtin_amdgcn_rcpf(den_h1)
                 + (GKC * va_w0) * __builtin_amdgcn_rcpf(den_w0)
                 + (GKC * va_w1) * __builtin_amdgcn_rcpf(den_w1);

            #pragma unroll
            for (int i = 0; i < KS - 1; ++i) {
                sh[i] = sh[i + 1]; ah[i] = ah[i + 1];
                sw[i] = sw[i + 1]; aw[i] = aw[i + 1];
            }
        }
    }

    // weight: exp(1 - gam[b]), constant per image
    const int b = img / CCH;
    double accd = (double)acc * (double)expf(1.0f - gam[b]);

    // block reduction in f64
    #pragma unroll
    for (int off = 32; off >= 1; off >>= 1)
        accd += __shfl_down(accd, off, 64);

    __shared__ double red[TPB / 64];
    const int lane = threadIdx.x & 63;
    const int wid  = threadIdx.x >> 6;
    if (lane == 0) red[wid] = accd;
    __syncthreads();
    if (threadIdx.x == 0) {
        double t = ((red[0] + red[1]) + (red[2] + red[3]))
                 + ((red[4] + red[5]) + (red[6] + red[7]));
        partial[(size_t)blockIdx.y * gridDim.x + blockIdx.x] = t;
    }
}

__global__ __launch_bounds__(256)
void rtv_reduce(const double* __restrict__ partial, int n,
                float* __restrict__ out)
{
    double acc = 0.0;
    for (int i = threadIdx.x; i < n; i += 256)
        acc += partial[i];

    #pragma unroll
    for (int off = 32; off >= 1; off >>= 1)
        acc += __shfl_down(acc, off, 64);

    __shared__ double red[4];
    const int lane = threadIdx.x & 63;
    const int wid  = threadIdx.x >> 6;
    if (lane == 0) red[wid] = acc;
    __syncthreads();
    if (threadIdx.x == 0) {
        double tot = (red[0] + red[1]) + (red[2] + red[3]);
        // mean over B*C*OH*OW = 48 * 1020*1020 elements (both terms share N)
        const double N = 48.0 * 1040400.0;
        out[0] = (float)(tot / N);
    }
}

extern "C" void kernel_launch(void* const* d_in, const int* in_sizes, int n_in,
                              void* d_out, int out_size, void* d_ws, size_t ws_size,
                              hipStream_t stream) {
    const float* gh  = (const float*)d_in[0];
    const float* gw  = (const float*)d_in[1];
    const float* gam = (const float*)d_in[2];
    float* out = (float*)d_out;
    double* ws = (double*)d_ws;

    dim3 grid(NCHUNK, NIMG);
    rtv_partial<<<grid, TPB, 0, stream>>>(gh, gw, gam, ws);

    const int nparts = NCHUNK * NIMG;   // 816
    rtv_reduce<<<1, 256, 0, stream>>>(ws, nparts, out);
}

// Round 11
// 113.754 us; speedup vs baseline: 1.2599x; 1.2599x over previous
//
#include <hip/hip_runtime.h>
#include <math.h>

#define HH 1024
#define WW 1024
#define OH 1020
#define OW 1020
#define KS 5
#define CHUNK 30      // 34*30 = 1020 exactly
#define NCHUNK 34
#define TPB 256
#define T 4           // output columns per thread
#define HALFW 128     // threads per plane-half; 128*T = 512 columns per x-tile
#define XTILES 2      // 2 * 512 = 1024 >= 1020
#define NIMG 48       // B*C = 16*3
#define CCH 3

// GK = 5 * sqrt(2*pi) * sigma^2, sigma=2
#define GKC 50.132565492620004f
#define EPSC 1e-6f
// Windows with |box_sum| below this get their sum recomputed in replicated
// numpy-f32 order (the ratio is rounding-noise-sensitive there).
#define RECOMP_T 1e-4f

// numpy order: inner (contiguous col) axis n=5 -> sequential fold; outer (row)
// axis -> sequential left-fold of the row sums. KEEP IDENTICAL (R3-R10 passed).
__device__ __forceinline__ float win25_np(const float* __restrict__ p) {
    float s = 0.0f;
    #pragma unroll
    for (int r = 0; r < KS; ++r) {
        const float* q = p + (size_t)r * WW;
        float t = q[0];
        t += q[1]; t += q[2]; t += q[3]; t += q[4];
        s += t;
    }
    return s;
}

// Load 8 consecutive floats (two float4), produce 4 horizontal 5-window sums
// (signed s[0..3], abs a[0..3]) shared incrementally across the 4 outputs.
// Identical to R4's load_row.
__device__ __forceinline__ void load_row(const float* __restrict__ row,
                                         float* __restrict__ s,
                                         float* __restrict__ a) {
    float4 u = *reinterpret_cast<const float4*>(row);
    float4 v = *reinterpret_cast<const float4*>(row + 4);
    float s0 = ((u.x + u.y) + (u.z + u.w)) + v.x;
    s[0] = s0;
    s[1] = s0   - u.x + v.y;
    s[2] = s[1] - u.y + v.z;
    s[3] = s[2] - u.z + v.w;
    float p0 = fabsf(u.x), p1 = fabsf(u.y), p2 = fabsf(u.z), p3 = fabsf(u.w);
    float q0 = fabsf(v.x), q1 = fabsf(v.y), q2 = fabsf(v.z), q3 = fabsf(v.w);
    float t0 = ((p0 + p1) + (p2 + p3)) + q0;
    a[0] = t0;
    a[1] = t0   - p0 + q1;
    a[2] = a[1] - p1 + q2;
    a[3] = a[2] - p2 + q3;
}

__global__ __launch_bounds__(TPB)   // natural VGPR; R7 showed pinning spills
void rtv_partial(const float* __restrict__ gh, const float* __restrict__ gw,
                 const float* __restrict__ gam, double* __restrict__ partial)
{
    const int tid  = (int)threadIdx.x;
    const int half = tid >> 7;              // 0: plane grad_h, 1: plane grad_w
    const int lt   = tid & (HALFW - 1);     // thread within the half
    const int x0   = blockIdx.x * (HALFW * T) + lt * T;  // first output column
    const int img  = blockIdx.z;            // b*C + c
    const int y0   = blockIdx.y * CHUNK;
    const int y1   = min(y0 + CHUNK, OH);   // runtime-opaque: keeps R4 body shape

    float acc = 0.0f;

    if (x0 < OW) {                          // last thread of tile 1 idle
        const float* __restrict__ p =
            (half ? gw : gh) + (size_t)img * HH * WW;

        // 5-slot rings of horizontal window sums for T outputs, ONE plane
        float hs[KS][T], ha[KS][T];
        #pragma unroll
        for (int i = 0; i < KS - 1; ++i)
            load_row(p + (size_t)(y0 + i) * WW + x0, hs[i], ha[i]);

        for (int yb = y0; yb < y1; yb += KS) {
            #pragma unroll
            for (int k = 0; k < KS; ++k) {
                const int y = yb + k;
                if (y < y1) {
                    const int snew = (k + 4) % KS;     // static after unroll
                    load_row(p + (size_t)(y + 4) * WW + x0, hs[snew], ha[snew]);

                    #pragma unroll
                    for (int j = 0; j < T; ++j) {
                        // fresh 5-tap vertical sums, same order as R3-R10
                        float vs = ((hs[k % KS][j] + hs[(k + 1) % KS][j])
                                  + (hs[(k + 2) % KS][j] + hs[(k + 3) % KS][j]))
                                  +  hs[(k + 4) % KS][j];
                        float va = ((ha[k % KS][j] + ha[(k + 1) % KS][j])
                                  + (ha[(k + 2) % KS][j] + ha[(k + 3) % KS][j]))
                                  +  ha[(k + 4) % KS][j];

                        float den;
                        if (__builtin_expect(fabsf(vs) < RECOMP_T, 0)) {
                            float s32 = win25_np(p + (size_t)y * WW + x0 + j);
                            den = fabsf(GKC * s32) + EPSC;
                        } else {
                            den = fabsf(GKC * vs) + EPSC;
                        }

                        acc += (GKC * va) * __builtin_amdgcn_rcpf(den);
                    }
                }
            }
        }
    }

    // weight: exp(1 - gam[b]), constant per image (same for both planes)
    const int b = img / CCH;
    double accd = (double)acc * (double)expf(1.0f - gam[b]);

    // block reduction in f64 (both halves into one block partial)
    #pragma unroll
    for (int off = 32; off >= 1; off >>= 1)
        accd += __shfl_down(accd, off, 64);

    __shared__ double red[TPB / 64];
    const int lane = tid & 63;
    const int wid  = tid >> 6;
    if (lane == 0) red[wid] = accd;
    __syncthreads();
    if (tid == 0) {
        double t = (red[0] + red[1]) + (red[2] + red[3]);
        partial[((size_t)blockIdx.z * gridDim.y + blockIdx.y) * gridDim.x
                + blockIdx.x] = t;
    }
}

__global__ __launch_bounds__(256)
void rtv_reduce(const double* __restrict__ partial, int n,
                float* __restrict__ out)
{
    double acc = 0.0;
    for (int i = threadIdx.x; i < n; i += 256)
        acc += partial[i];

    #pragma unroll
    for (int off = 32; off >= 1; off >>= 1)
        acc += __shfl_down(acc, off, 64);

    __shared__ double red[4];
    const int lane = threadIdx.x & 63;
    const int wid  = threadIdx.x >> 6;
    if (lane == 0) red[wid] = acc;
    __syncthreads();
    if (threadIdx.x == 0) {
        double tot = (red[0] + red[1]) + (red[2] + red[3]);
        // mean over B*C*OH*OW = 48 * 1020*1020 elements (both terms share N)
        const double N = 48.0 * 1040400.0;
        out[0] = (float)(tot / N);
    }
}

extern "C" void kernel_launch(void* const* d_in, const int* in_sizes, int n_in,
                              void* d_out, int out_size, void* d_ws, size_t ws_size,
                              hipStream_t stream) {
    const float* gh  = (const float*)d_in[0];
    const float* gw  = (const float*)d_in[1];
    const float* gam = (const float*)d_in[2];
    float* out = (float*)d_out;
    double* ws = (double*)d_ws;

    dim3 grid(XTILES, NCHUNK, NIMG);    // 2 * 34 * 48 = 3264 blocks
    rtv_partial<<<grid, TPB, 0, stream>>>(gh, gw, gam, ws);

    const int nparts = XTILES * NCHUNK * NIMG;   // 3264 doubles = 26 KB of ws
    rtv_reduce<<<1, 256, 0, stream>>>(ws, nparts, out);
}